// Round 9
// baseline (211.148 us; speedup 1.0000x reference)
//
#include <hip/hip_runtime.h>

// Problem constants (B=4, H=W=64, C=D=512, heads=8, hd=64, SR=2)
// N = 4096 queries, Nk = 1024 keys.

typedef __attribute__((ext_vector_type(8))) _Float16 f16x8;
typedef __attribute__((ext_vector_type(4))) _Float16 f16x4;
typedef __attribute__((ext_vector_type(4))) float f32x4;

#define EXP2F(x) __builtin_amdgcn_exp2f(x)

// async global->LDS, 16B per lane; LDS dest = wave-uniform base + lane*16
__device__ __forceinline__ void gload_lds16(const _Float16* g, _Float16* l)
{
    __builtin_amdgcn_global_load_lds(
        (const __attribute__((address_space(1))) void*)g,
        (__attribute__((address_space(3))) void*)l, 16, 0, 0);
}

template<int N>
__device__ __forceinline__ void wait_vm()
{
    asm volatile("s_waitcnt vmcnt(%0)" :: "n"(N) : "memory");
}

// ---------------------------------------------------------------------------
// Fused prep: blocks [0,4096) x fp32->fp16; [4096,5120) 4x weight transpose;
// [5120,6144) srw transpose. All independent memory-bound work, one launch.
// ---------------------------------------------------------------------------
__global__ __launch_bounds__(256)
void prep_k(const float* __restrict__ x,
            const float* __restrict__ Wq, const float* __restrict__ Wk,
            const float* __restrict__ Wv, const float* __restrict__ Wp,
            const float* __restrict__ srw,
            _Float16* __restrict__ xh, _Float16* __restrict__ wqt,
            _Float16* __restrict__ wkvt, _Float16* __restrict__ wpt,
            _Float16* __restrict__ srwt)
{
    __shared__ float T[32][33];
    const int id = blockIdx.x;
    const int t = threadIdx.x;

    if (id < 4096) {                       // ---- x fp32 -> fp16 ----
        const size_t i = ((size_t)id * 256 + t) * 8;
        const float4 a = *(const float4*)(x + i);
        const float4 b = *(const float4*)(x + i + 4);
        f16x8 o;
        o[0] = (_Float16)a.x; o[1] = (_Float16)a.y; o[2] = (_Float16)a.z; o[3] = (_Float16)a.w;
        o[4] = (_Float16)b.x; o[5] = (_Float16)b.y; o[6] = (_Float16)b.z; o[7] = (_Float16)b.w;
        *(f16x8*)(xh + i) = o;
        return;
    }

    if (id < 5120) {                       // ---- 4x 512x512 transpose ----
        const int id2 = id - 4096;
        const int z = id2 >> 8, k0 = ((id2 >> 4) & 15) * 32, n0 = (id2 & 15) * 32;
        const float* src; _Float16* dst; int perm;
        switch (z) {
            case 0:  src = Wq; dst = wqt;           perm = 1; break;
            case 1:  src = Wk; dst = wkvt;          perm = 1; break;
            case 2:  src = Wv; dst = wkvt + 262144; perm = 0; break;
            default: src = Wp; dst = wpt;           perm = 0; break;
        }
        {
            const int r = t >> 3, c = (t & 7) * 4;
            const float4 v = *(const float4*)(src + (size_t)(k0 + r) * 512 + n0 + c);
            T[r][c + 0] = v.x; T[r][c + 1] = v.y; T[r][c + 2] = v.z; T[r][c + 3] = v.w;
        }
        __syncthreads();
        {
            const int j = t >> 3, i0 = (t & 7) * 4;
            const int n = n0 + j;
            const int nper = perm ? ((n & 7) * 64 + (n >> 3)) : n;
            f16x4 o;
            o[0] = (_Float16)T[i0 + 0][j];
            o[1] = (_Float16)T[i0 + 1][j];
            o[2] = (_Float16)T[i0 + 2][j];
            o[3] = (_Float16)T[i0 + 3][j];
            *(f16x4*)(dst + (size_t)nper * 512 + k0 + i0) = o;
        }
        return;
    }

    {                                      // ---- srw [2048][512] -> [512][2048] ----
        const int id3 = id - 5120;
        const int n0 = (id3 & 15) * 32, k0 = (id3 >> 4) * 32;
        {
            const int r = t >> 3, c = (t & 7) * 4;
            const float4 v = *(const float4*)(srw + (size_t)(k0 + r) * 512 + n0 + c);
            T[r][c + 0] = v.x; T[r][c + 1] = v.y; T[r][c + 2] = v.z; T[r][c + 3] = v.w;
        }
        __syncthreads();
        {
            const int j = t >> 3, i0 = (t & 7) * 4;
            f16x4 o;
            o[0] = (_Float16)T[i0 + 0][j];
            o[1] = (_Float16)T[i0 + 1][j];
            o[2] = (_Float16)T[i0 + 2][j];
            o[3] = (_Float16)T[i0 + 3][j];
            *(f16x4*)(srwt + (size_t)(n0 + j) * 2048 + k0 + i0) = o;
        }
        return;
    }
}

// ---------------------------------------------------------------------------
// fp16 MFMA GEMM body, NBUF-deep pipeline, counted vmcnt, ONE raw barrier
// per K-step (T3+T4). P=NBUF-1 tiles in flight. (Used by convq + out-proj.)
// ---------------------------------------------------------------------------
template<int MODE, bool CONV, int BM>
__device__ __forceinline__ void gemm_body(
    const int bx, const int by,
    const _Float16* __restrict__ A, const _Float16* __restrict__ Wt,
    const float* __restrict__ bias, const float* __restrict__ bias2,
    void* __restrict__ Cv, void* __restrict__ Cv2,
    _Float16* __restrict__ As, _Float16* __restrict__ Ws)
{
    constexpr int K = CONV ? 2048 : 512;
    constexpr int NIT = K / 32;
    constexpr int MT = BM / 32;          // row-tiles per wave
    constexpr int AI = BM / 64;          // A staging instrs per wave
    constexpr int ABUF = BM * 32;        // elems per A buffer
    constexpr int NBUF = (BM == 64) ? 4 : 3;
    constexpr int P = NBUF - 1;          // tiles in flight
    constexpr int L = AI + 2;            // loads per stage per wave
    const int tid = threadIdx.x;
    const int wave = tid >> 6, lane = tid & 63;
    const int quad = lane >> 4, l15 = lane & 15;
    const int wm = wave >> 1, wn = wave & 1;
    const int wrow = wm * (BM / 2);
    const int m0 = by * BM, n0 = bx * 128;

    // ---- hoisted staging bases (k-independent) ----
    const _Float16* abase[AI];
    int ac8[AI];
    #pragma unroll
    for (int t = 0; t < AI; ++t) {
        const int e = (wave * AI + t) * 64 + lane;
        const int row = e >> 2, c8 = (e & 3) * 8;
        ac8[t] = c8;
        if (CONV) {
            const int grow = m0 + row;
            const int b = grow >> 10, rem = grow & 1023;
            const int oh = rem >> 5, ow = rem & 31;
            abase[t] = A + ((size_t)((b * 64 + 2 * oh) * 64) + 2 * ow) * 512;
        } else {
            abase[t] = A + (size_t)(m0 + row) * K + c8;
        }
    }
    const _Float16* wbase[2];
    #pragma unroll
    for (int t = 0; t < 2; ++t) {
        const int e = (wave * 2 + t) * 64 + lane;
        const int row = e >> 2, c8 = (e & 3) * 8;
        wbase[t] = Wt + (size_t)(n0 + row) * K + c8;
    }

    auto stage = [&](const int k0, const int buf) {
        #pragma unroll
        for (int t = 0; t < AI; ++t) {
            const _Float16* gp;
            if (CONV) {
                const int gk = k0 + ac8[t];
                gp = abase[t] + ((gk >> 10) & 1) * 32768 + ((gk >> 9) & 1) * 512
                              + (gk & 511);
            } else {
                gp = abase[t] + k0;
            }
            gload_lds16(gp, &As[buf * ABUF + (wave * AI + t) * 512]);
        }
        #pragma unroll
        for (int t = 0; t < 2; ++t)
            gload_lds16(wbase[t] + k0, &Ws[buf * 4096 + (wave * 2 + t) * 512]);
    };

    f32x4 acc[MT][4] = {};

    #pragma unroll
    for (int p = 0; p < P; ++p) stage(p * 32, p);

    int cur = 0, nxt = P % NBUF;
    for (int it = 0; it < NIT; ++it) {
        int rem = NIT - 1 - it;
        if (rem > P - 1) rem = P - 1;
        switch (rem) {                       // tile it landed; newer stay in flight
            case 0:  wait_vm<0>(); break;
            case 1:  wait_vm<L>(); break;
            case 2:  wait_vm<2 * L>(); break;
            default: wait_vm<3 * L>(); break;
        }
        __builtin_amdgcn_s_barrier();
        __builtin_amdgcn_sched_barrier(0);
        if (it + P < NIT) {
            stage((it + P) * 32, nxt);
            nxt = (nxt + 1 == NBUF) ? 0 : nxt + 1;
        }

        f16x8 af[MT], bf[4];
        #pragma unroll
        for (int mt = 0; mt < MT; ++mt)
            af[mt] = *(const f16x8*)&As[cur * ABUF + (wrow + mt * 16 + l15) * 32 + quad * 8];
        #pragma unroll
        for (int nt = 0; nt < 4; ++nt)
            bf[nt] = *(const f16x8*)&Ws[cur * 4096 + (wn * 64 + nt * 16 + l15) * 32 + quad * 8];
        #pragma unroll
        for (int mt = 0; mt < MT; ++mt)
            #pragma unroll
            for (int nt = 0; nt < 4; ++nt)
                acc[mt][nt] = __builtin_amdgcn_mfma_f32_16x16x32_f16(
                    af[mt], bf[nt], acc[mt][nt], 0, 0, 0);

        cur = (cur + 1 == NBUF) ? 0 : cur + 1;
    }

    // ---- epilogue: C/D layout col=lane&15, row=quad*4+reg ----
    #pragma unroll
    for (int nt = 0; nt < 4; ++nt) {
        const int gcol = n0 + wn * 64 + nt * 16 + l15;
        float bv;
        if (MODE == 6) bv = bias[(gcol & 63) * 8 + (gcol >> 6)];
        else bv = bias[gcol];
        #pragma unroll
        for (int mt = 0; mt < MT; ++mt) {
            const int row0 = m0 + wrow + mt * 16 + quad * 4;
            if (MODE == 0) {
                #pragma unroll
                for (int r = 0; r < 4; ++r)
                    ((float*)Cv)[(size_t)(row0 + r) * 512 + gcol] = acc[mt][nt][r] + bv;
            } else {
                #pragma unroll
                for (int r = 0; r < 4; ++r)
                    ((_Float16*)Cv)[(size_t)(row0 + r) * 512 + gcol] =
                        (_Float16)(acc[mt][nt][r] + bv);
            }
        }
    }
}

template<int MODE, bool CONV, int BM>
__global__ __launch_bounds__(256)
void gemm_f16(const _Float16* __restrict__ A, const _Float16* __restrict__ Wt,
              const float* __restrict__ bias, const float* __restrict__ bias2,
              void* __restrict__ Cv, void* __restrict__ Cv2)
{
    __shared__ __align__(16) _Float16 lds[24576];   // 48 KB
    constexpr int NBUF = (BM == 64) ? 4 : 3;
    gemm_body<MODE, CONV, BM>(blockIdx.x, blockIdx.y, A, Wt, bias, bias2,
                              Cv, Cv2, lds, lds + NBUF * BM * 32);
}

// ---------------------------------------------------------------------------
// Fused conv (im2col GEMM, 256 blocks, FIRST: K=2048 long pole) + Q
// projection (512 blocks): both read xh, independent -> one launch (3 blk/CU).
// ---------------------------------------------------------------------------
__global__ __launch_bounds__(256)
void convq_k(const _Float16* __restrict__ xh, const _Float16* __restrict__ srwt,
             const float* __restrict__ srb, const _Float16* __restrict__ wqt,
             const float* __restrict__ bq,
             _Float16* __restrict__ kvh, _Float16* __restrict__ qh)
{
    __shared__ __align__(16) _Float16 lds[24576];   // 48 KB
    const int id = blockIdx.x;
    if (id < 256) {        // conv: grid (4,64), K=2048, NBUF=4
        gemm_body<4, true, 64>(id & 3, id >> 2, xh, srwt, srb, nullptr,
                               kvh, nullptr, lds, lds + 4 * 64 * 32);
    } else {               // Q proj: grid (4,128), NBUF=3
        const int id2 = id - 256;
        gemm_body<6, false, 128>(id2 & 3, id2 >> 2, xh, wqt, bq, nullptr,
                                 qh, nullptr, lds, lds + 3 * 128 * 32);
    }
}

// ---------------------------------------------------------------------------
// LN-fused KV projection. grid (8,64), 256 thr, 2 blocks/CU (80KB LDS).
// Phase 1: LN per row into a resident XOR-swizzled 64KB LDS tile.
// Phase 2: K-loop, zero A staging, 8KB W dbuf. Epilogue = MODE 5.
// ---------------------------------------------------------------------------
__global__ __launch_bounds__(256)
void kvln_k(const _Float16* __restrict__ A, const _Float16* __restrict__ Wt,
            const float* __restrict__ lng, const float* __restrict__ lnb,
            const float* __restrict__ biask, const float* __restrict__ biasv,
            _Float16* __restrict__ kh, _Float16* __restrict__ vh)
{
    __shared__ __align__(16) _Float16 Al[64 * 512];    // 64KB resident A
    __shared__ __align__(16) _Float16 Ws[2 * 4096];    // 16KB W dbuf
    const int bx = blockIdx.x, by = blockIdx.y;
    const int tid = threadIdx.x;
    const int wave = tid >> 6, lane = tid & 63;
    const int quad = lane >> 4, l15 = lane & 15;
    const int wm = wave >> 1, wn = wave & 1;
    const int wrow = wm * 32;
    const int m0 = by * 64, n0 = bx * 128;

    // ---- W staging (identical layout to gemm_body) ----
    const _Float16* wbase[2];
    #pragma unroll
    for (int t = 0; t < 2; ++t) {
        const int e = (wave * 2 + t) * 64 + lane;
        const int row = e >> 2, c8 = (e & 3) * 8;
        wbase[t] = Wt + (size_t)(n0 + row) * 512 + c8;
    }
    auto stageW = [&](const int k0, const int buf) {
        #pragma unroll
        for (int t = 0; t < 2; ++t)
            gload_lds16(wbase[t] + k0, &Ws[buf * 4096 + (wave * 2 + t) * 512]);
    };
    stageW(0, 0);                           // W tile 0 flies during LN phase

    // ---- Phase 1: load A, LayerNorm, swizzled resident store ----
    const int colt = (tid & 63) * 8;        // fixed column span per thread
    float g[8], bb[8];
    {
        const float4 g0 = *(const float4*)(lng + colt);
        const float4 g1 = *(const float4*)(lng + colt + 4);
        const float4 b0 = *(const float4*)(lnb + colt);
        const float4 b1 = *(const float4*)(lnb + colt + 4);
        g[0] = g0.x; g[1] = g0.y; g[2] = g0.z; g[3] = g0.w;
        g[4] = g1.x; g[5] = g1.y; g[6] = g1.z; g[7] = g1.w;
        bb[0] = b0.x; bb[1] = b0.y; bb[2] = b0.z; bb[3] = b0.w;
        bb[4] = b1.x; bb[5] = b1.y; bb[6] = b1.z; bb[7] = b1.w;
    }
    const _Float16* ab = A + (size_t)m0 * 512;
    #pragma unroll
    for (int r4 = 0; r4 < 4; ++r4) {
        float f[4][8]; float mu[4], rs[4];
        #pragma unroll
        for (int i = 0; i < 4; ++i) {
            const int c = (r4 * 4 + i) * 256 + tid;
            const f16x8 d = *(const f16x8*)(ab + (size_t)c * 8);
            #pragma unroll
            for (int e = 0; e < 8; ++e) f[i][e] = (float)d[e];
        }
        #pragma unroll
        for (int i = 0; i < 4; ++i) {
            float s = 0.f, q = 0.f;
            #pragma unroll
            for (int e = 0; e < 8; ++e) { s += f[i][e]; q += f[i][e] * f[i][e]; }
            #pragma unroll
            for (int off = 32; off > 0; off >>= 1) {
                s += __shfl_xor(s, off);
                q += __shfl_xor(q, off);
            }
            mu[i] = s * (1.f / 512.f);
            rs[i] = rsqrtf(fmaxf(q * (1.f / 512.f) - mu[i] * mu[i], 0.f) + 1e-6f);
        }
        #pragma unroll
        for (int i = 0; i < 4; ++i) {
            const int row = (r4 * 4 + i) * 4 + wave;   // == c>>6
            f16x8 o;
            #pragma unroll
            for (int e = 0; e < 8; ++e)
                o[e] = (_Float16)((f[i][e] - mu[i]) * rs[i] * g[e] + bb[e]);
            const int boff = (row * 1024 + colt * 2) ^ ((row & 7) << 4);
            *(f16x8*)((char*)Al + boff) = o;
        }
    }
    __syncthreads();                        // Al valid; W tile 0 landed too

    // ---- Phase 2: K-loop, A resident, W dbuf ----
    f32x4 acc[2][4] = {};
    int cur = 0;
    for (int it = 0; it < 16; ++it) {
        if (it) {
            wait_vm<0>();                   // W[cur] landed
            __builtin_amdgcn_s_barrier();   // prev readers of other buf done
        }
        if (it + 1 < 16) stageW((it + 1) * 32, cur ^ 1);
        const int k0 = it * 32;
        f16x8 af[2], bf[4];
        #pragma unroll
        for (int mt = 0; mt < 2; ++mt) {
            const int row = wrow + mt * 16 + l15;
            const int boff = (row * 1024 + k0 * 2 + quad * 16) ^ ((row & 7) << 4);
            af[mt] = *(const f16x8*)((const char*)Al + boff);
        }
        #pragma unroll
        for (int nt = 0; nt < 4; ++nt)
            bf[nt] = *(const f16x8*)&Ws[cur * 4096 + (wn * 64 + nt * 16 + l15) * 32 + quad * 8];
        #pragma unroll
        for (int mt = 0; mt < 2; ++mt)
            #pragma unroll
            for (int nt = 0; nt < 4; ++nt)
                acc[mt][nt] = __builtin_amdgcn_mfma_f32_16x16x32_f16(
                    af[mt], bf[nt], acc[mt][nt], 0, 0, 0);
        cur ^= 1;
    }

    // ---- epilogue: MODE 5 (k<512 head-perm'd -> kh; else v^T -> vh) ----
    #pragma unroll
    for (int nt = 0; nt < 4; ++nt) {
        const int gcol = n0 + wn * 64 + nt * 16 + l15;
        const float bv = (gcol < 512) ? biask[(gcol & 63) * 8 + (gcol >> 6)]
                                      : biasv[gcol - 512];
        #pragma unroll
        for (int mt = 0; mt < 2; ++mt) {
            const int row0 = m0 + wrow + mt * 16 + quad * 4;
            if (gcol < 512) {
                #pragma unroll
                for (int r = 0; r < 4; ++r)
                    kh[(size_t)(row0 + r) * 512 + gcol] =
                        (_Float16)(acc[mt][nt][r] + bv);
            } else {
                const int c = gcol - 512;
                const int h = c & 7, d = c >> 3;
                const int b_ = row0 >> 10, jj = row0 & 1023;
                f16x4 o;
                #pragma unroll
                for (int r = 0; r < 4; ++r) o[r] = (_Float16)(acc[mt][nt][r] + bv);
                *(f16x4*)(vh + ((size_t)(b_ * 8 + h) * 64 + d) * 1024 + jj) = o;
            }
        }
    }
}

// ---------------------------------------------------------------------------
// MFMA flash attention v9: v8 structure (8 waves, 512 q-rows, 4 subtiles,
// grid (8,32), perm'd-K x32 PV, ones-MFMA l-sum) + PIPE OVERLAP:
//  (1) within-wave 2-stage pipeline over the two 32-key halves: QK(A)+exp(A)
//      -> QK(B)[MFMA] -> lsum(A) -> exp(B)[VALU] -> PV(A)[MFMA] -> lsum/PV(B).
//      exp(B) is independent of PV(A) -> scheduler interleaves VALU with MFMA.
//  (2) inter-wave anti-phase: waves 4-7 process halves in opposite order, so
//      the two waves on each SIMD hit opposite pipes at any time.
// Prior serialized pipes: MFMA 14.7us + VALU 14us + LDS 11.5us ~= 42.8us.
// ---------------------------------------------------------------------------
__global__ __launch_bounds__(512)
void attn_mfma_k(const _Float16* __restrict__ qb,
                 const _Float16* __restrict__ kbuf,
                 const _Float16* __restrict__ vbuf,
                 _Float16* __restrict__ out)
{
    const int bh = blockIdx.y;           // 0..31
    const int qt = blockIdx.x;           // 0..7
    const int b = bh >> 3, h = bh & 7;
    const int tid = threadIdx.x;
    const int wave = tid >> 6, lane = tid & 63;
    const int quad = lane >> 4, l15 = lane & 15;

    __shared__ __align__(16) _Float16 Ks[2][64 * 72];   // [perm'd key][d]
    __shared__ __align__(16) _Float16 Vs[2][64 * 72];   // [d][key]

    // ---- Q frags (B operand), pre-scaled by 0.125*log2(e) ----
    const int qrow = b * 4096 + qt * 512 + wave * 64 + l15;
    const _Float16* qp = qb + (size_t)qrow * 512 + h * 64 + quad * 8;
    f16x8 qf[4][2];
    #pragma unroll
    for (int su = 0; su < 4; ++su) {
        qf[su][0] = *(const f16x8*)(qp + su * 16 * 512);
        qf[su][1] = *(const f16x8*)(qp + su * 16 * 512 + 32);
    }
    {
        const _Float16 qs = (_Float16)0.18033688f;
        #pragma unroll
        for (int su = 0; su < 4; ++su)
            #pragma unroll
            for (int g = 0; g < 2; ++g)
                #pragma unroll
                for (int i = 0; i < 8; ++i) qf[su][g][i] *= qs;
    }

    // ---- ones B-frag for the l-sum MFMA ----
    f16x8 ones;
    #pragma unroll
    for (int i = 0; i < 8; ++i) ones[i] = (_Float16)1.0f;

    // ---- staging pointers: 512 thr x 16B = one 64x64 fp16 tile ----
    const int kr = tid >> 3, kc = (tid & 7) * 8;
    // permuted K LDS row: key kr -> row so S^T lands pre-arranged for x32 PV
    const int krp = (kr & 32) | ((kr & 4) << 2) | ((kr >> 1) & 12) | (kr & 3);
    const _Float16* kg = kbuf + (size_t)(b * 1024 + kr) * 512 + h * 64 + kc;
    const _Float16* vg = vbuf + (size_t)(bh * 64 + kr) * 1024 + kc;

    f16x8 krg = *(const f16x8*)kg;
    f16x8 vrg = *(const f16x8*)vg;
    *(f16x8*)&Ks[0][krp * 72 + kc] = krg;
    *(f16x8*)&Vs[0][kr * 72 + kc] = vrg;

    f32x4 acc[4][4] = {};
    f32x4 acc_l[4] = {};

    const int kbA = (wave >> 2) & 1;     // waves 4-7 anti-phased
    const int kbB = kbA ^ 1;

    for (int kt = 0; kt < 16; ++kt) {
        const int cur = kt & 1;
        __syncthreads();                               // buf[cur] staged, buf[cur^1] free
        if (kt < 15) {                                 // prefetch next chunk
            krg = *(const f16x8*)(kg + (size_t)(kt + 1) * 64 * 512);
            vrg = *(const f16x8*)(vg + (kt + 1) * 64);
        }

        // ---- stage 1: QK + exp for half A ----
        f16x8 paA[4];
        #pragma unroll
        for (int c = 0; c < 2; ++c) {
            const int ct = kbA * 2 + c;
            const f16x8 kf0 = *(const f16x8*)&Ks[cur][(ct * 16 + l15) * 72 + quad * 8];
            const f16x8 kf1 = *(const f16x8*)&Ks[cur][(ct * 16 + l15) * 72 + 32 + quad * 8];
            #pragma unroll
            for (int su = 0; su < 4; ++su) {
                f32x4 s = {};
                s = __builtin_amdgcn_mfma_f32_16x16x32_f16(kf0, qf[su][0], s, 0, 0, 0);
                s = __builtin_amdgcn_mfma_f32_16x16x32_f16(kf1, qf[su][1], s, 0, 0, 0);
                paA[su][c * 4 + 0] = (_Float16)EXP2F(s[0]);
                paA[su][c * 4 + 1] = (_Float16)EXP2F(s[1]);
                paA[su][c * 4 + 2] = (_Float16)EXP2F(s[2]);
                paA[su][c * 4 + 3] = (_Float16)EXP2F(s[3]);
            }
        }

        // ---- stage 2: QK (MFMA only) for half B into live S regs ----
        f32x4 sB[4][2];
        #pragma unroll
        for (int c = 0; c < 2; ++c) {
            const int ct = kbB * 2 + c;
            const f16x8 kf0 = *(const f16x8*)&Ks[cur][(ct * 16 + l15) * 72 + quad * 8];
            const f16x8 kf1 = *(const f16x8*)&Ks[cur][(ct * 16 + l15) * 72 + 32 + quad * 8];
            #pragma unroll
            for (int su = 0; su < 4; ++su) {
                f32x4 s = {};
                s = __builtin_amdgcn_mfma_f32_16x16x32_f16(kf0, qf[su][0], s, 0, 0, 0);
                sB[su][c] = __builtin_amdgcn_mfma_f32_16x16x32_f16(kf1, qf[su][1], s, 0, 0, 0);
            }
        }

        // ---- stage 3: lsum(A); exp(B) [VALU, overlaps PV(A) MFMAs]; PV(A) ----
        __builtin_amdgcn_s_setprio(1);
        #pragma unroll
        for (int su = 0; su < 4; ++su)
            acc_l[su] = __builtin_amdgcn_mfma_f32_16x16x32_f16(
                paA[su], ones, acc_l[su], 0, 0, 0);
        f16x8 paB[4];
        #pragma unroll
        for (int su = 0; su < 4; ++su)
            #pragma unroll
            for (int c = 0; c < 2; ++c) {
                paB[su][c * 4 + 0] = (_Float16)EXP2F(sB[su][c][0]);
                paB[su][c * 4 + 1] = (_Float16)EXP2F(sB[su][c][1]);
                paB[su][c * 4 + 2] = (_Float16)EXP2F(sB[su][c][2]);
                paB[su][c * 4 + 3] = (_Float16)EXP2F(sB[su][c][3]);
            }
        #pragma unroll
        for (int nt = 0; nt < 4; ++nt) {
            const f16x8 vf = *(const f16x8*)&Vs[cur][(nt * 16 + l15) * 72 + kbA * 32 + quad * 8];
            #pragma unroll
            for (int su = 0; su < 4; ++su)
                acc[su][nt] = __builtin_amdgcn_mfma_f32_16x16x32_f16(
                    paA[su], vf, acc[su][nt], 0, 0, 0);
        }

        // ---- stage 4: lsum(B) + PV(B) ----
        #pragma unroll
        for (int su = 0; su < 4; ++su)
            acc_l[su] = __builtin_amdgcn_mfma_f32_16x16x32_f16(
                paB[su], ones, acc_l[su], 0, 0, 0);
        #pragma unroll
        for (int nt = 0; nt < 4; ++nt) {
            const f16x8 vf = *(const f16x8*)&Vs[cur][(nt * 16 + l15) * 72 + kbB * 32 + quad * 8];
            #pragma unroll
            for (int su = 0; su < 4; ++su)
                acc[su][nt] = __builtin_amdgcn_mfma_f32_16x16x32_f16(
                    paB[su], vf, acc[su][nt], 0, 0, 0);
        }
        __builtin_amdgcn_s_setprio(0);

        if (kt < 15) {                                 // write prefetch -> other buf
            *(f16x8*)&Ks[cur ^ 1][krp * 72 + kc] = krg;
            *(f16x8*)&Vs[cur ^ 1][kr * 72 + kc] = vrg;
        }
    }

    // ---- epilogue: l[q] sits in acc_l[su][r] at exactly (quad,r) of row q ----
    #pragma unroll
    for (int su = 0; su < 4; ++su) {
        float inv[4];
        #pragma unroll
        for (int r = 0; r < 4; ++r) inv[r] = 1.0f / acc_l[su][r];
        #pragma unroll
        for (int nt = 0; nt < 4; ++nt)
            #pragma unroll
            for (int r = 0; r < 4; ++r) {
                const int row = qt * 512 + wave * 64 + su * 16 + quad * 4 + r;
                const int col = h * 64 + nt * 16 + l15;
                out[((size_t)b * 4096 + row) * 512 + col] =
                    (_Float16)(acc[su][nt][r] * inv[r]);
            }
    }
}

// ---------------------------------------------------------------------------
extern "C" void kernel_launch(void* const* d_in, const int* in_sizes, int n_in,
                              void* d_out, int out_size, void* d_ws, size_t ws_size,
                              hipStream_t stream)
{
    const float* x   = (const float*)d_in[0];
    const float* Wq  = (const float*)d_in[1];
    const float* bq  = (const float*)d_in[2];
    const float* Wk  = (const float*)d_in[3];
    const float* bk  = (const float*)d_in[4];
    const float* Wv  = (const float*)d_in[5];
    const float* bv  = (const float*)d_in[6];
    const float* Wp  = (const float*)d_in[7];
    const float* bp  = (const float*)d_in[8];
    const float* srw = (const float*)d_in[9];
    const float* srb = (const float*)d_in[10];
    const float* lng = (const float*)d_in[11];
    const float* lnb = (const float*)d_in[12];

    _Float16* ws   = (_Float16*)d_ws;
    _Float16* xh   = ws;                    // 8,388,608  (16.8 MB)
    _Float16* atth = xh + 8388608;          // 8,388,608  (16.8 MB)
    _Float16* kvh  = atth + 8388608;        // 2,097,152  (4.2 MB)
    _Float16* kh   = kvh + 2097152;         // 2,097,152  (4.2 MB)
    _Float16* vh   = kh + 2097152;          // 2,097,152  (4.2 MB)
    _Float16* wqt  = vh + 2097152;          // 262,144
    _Float16* wkvt = wqt + 262144;          // 524,288 (Wk perm'd | Wv plain)
    _Float16* wpt  = wkvt + 524288;         // 262,144
    _Float16* srwt = wpt + 262144;          // 1,048,576
    _Float16* qh   = (_Float16*)d_out;      // q scratch in d_out

    // 1. fused prep: cvt + 4x weight transpose + srw transpose
    prep_k<<<6144, 256, 0, stream>>>(x, Wq, Wk, Wv, Wp, srw,
                                     xh, wqt, wkvt, wpt, srwt);
    // 2. fused conv (im2col GEMM, first) + Q projection
    convq_k<<<768, 256, 0, stream>>>(xh, srwt, srb, wqt, bq, kvh, qh);
    // 3. LN-fused K+V projections (512 blocks, 2/CU, A resident in LDS)
    kvln_k<<<dim3(8, 64), 256, 0, stream>>>(kvh, wkvt, lng, lnb, bk, bv, kh, vh);
    // 4. MFMA flash attention (pipelined halves + anti-phase waves)
    attn_mfma_k<<<dim3(8, 32), 512, 0, stream>>>(qh, kh, vh, atth);
    // 5. output projection -> d_out fp32
    gemm_f16<0, false, 128><<<dim3(4, 128), 256, 0, stream>>>(
        atth, wpt, bp, nullptr, d_out, nullptr);
}

// Round 10
// 209.606 us; speedup vs baseline: 1.0074x; 1.0074x over previous
//
#include <hip/hip_runtime.h>

// Problem constants (B=4, H=W=64, C=D=512, heads=8, hd=64, SR=2)
// N = 4096 queries, Nk = 1024 keys.

typedef __attribute__((ext_vector_type(8))) _Float16 f16x8;
typedef __attribute__((ext_vector_type(4))) _Float16 f16x4;
typedef __attribute__((ext_vector_type(4))) float f32x4;

#define EXP2F(x) __builtin_amdgcn_exp2f(x)

// async global->LDS, 16B per lane; LDS dest = wave-uniform base + lane*16
__device__ __forceinline__ void gload_lds16(const _Float16* g, _Float16* l)
{
    __builtin_amdgcn_global_load_lds(
        (const __attribute__((address_space(1))) void*)g,
        (__attribute__((address_space(3))) void*)l, 16, 0, 0);
}

template<int N>
__device__ __forceinline__ void wait_vm()
{
    asm volatile("s_waitcnt vmcnt(%0)" :: "n"(N) : "memory");
}

// ---------------------------------------------------------------------------
// Fused prep: blocks [0,4096) x fp32->fp16; [4096,5120) 4x weight transpose;
// [5120,6144) srw transpose. All independent memory-bound work, one launch.
// ---------------------------------------------------------------------------
__global__ __launch_bounds__(256)
void prep_k(const float* __restrict__ x,
            const float* __restrict__ Wq, const float* __restrict__ Wk,
            const float* __restrict__ Wv, const float* __restrict__ Wp,
            const float* __restrict__ srw,
            _Float16* __restrict__ xh, _Float16* __restrict__ wqt,
            _Float16* __restrict__ wkvt, _Float16* __restrict__ wpt,
            _Float16* __restrict__ srwt)
{
    __shared__ float T[32][33];
    const int id = blockIdx.x;
    const int t = threadIdx.x;

    if (id < 4096) {                       // ---- x fp32 -> fp16 ----
        const size_t i = ((size_t)id * 256 + t) * 8;
        const float4 a = *(const float4*)(x + i);
        const float4 b = *(const float4*)(x + i + 4);
        f16x8 o;
        o[0] = (_Float16)a.x; o[1] = (_Float16)a.y; o[2] = (_Float16)a.z; o[3] = (_Float16)a.w;
        o[4] = (_Float16)b.x; o[5] = (_Float16)b.y; o[6] = (_Float16)b.z; o[7] = (_Float16)b.w;
        *(f16x8*)(xh + i) = o;
        return;
    }

    if (id < 5120) {                       // ---- 4x 512x512 transpose ----
        const int id2 = id - 4096;
        const int z = id2 >> 8, k0 = ((id2 >> 4) & 15) * 32, n0 = (id2 & 15) * 32;
        const float* src; _Float16* dst; int perm;
        switch (z) {
            case 0:  src = Wq; dst = wqt;           perm = 1; break;
            case 1:  src = Wk; dst = wkvt;          perm = 1; break;
            case 2:  src = Wv; dst = wkvt + 262144; perm = 0; break;
            default: src = Wp; dst = wpt;           perm = 0; break;
        }
        {
            const int r = t >> 3, c = (t & 7) * 4;
            const float4 v = *(const float4*)(src + (size_t)(k0 + r) * 512 + n0 + c);
            T[r][c + 0] = v.x; T[r][c + 1] = v.y; T[r][c + 2] = v.z; T[r][c + 3] = v.w;
        }
        __syncthreads();
        {
            const int j = t >> 3, i0 = (t & 7) * 4;
            const int n = n0 + j;
            const int nper = perm ? ((n & 7) * 64 + (n >> 3)) : n;
            f16x4 o;
            o[0] = (_Float16)T[i0 + 0][j];
            o[1] = (_Float16)T[i0 + 1][j];
            o[2] = (_Float16)T[i0 + 2][j];
            o[3] = (_Float16)T[i0 + 3][j];
            *(f16x4*)(dst + (size_t)nper * 512 + k0 + i0) = o;
        }
        return;
    }

    {                                      // ---- srw [2048][512] -> [512][2048] ----
        const int id3 = id - 5120;
        const int n0 = (id3 & 15) * 32, k0 = (id3 >> 4) * 32;
        {
            const int r = t >> 3, c = (t & 7) * 4;
            const float4 v = *(const float4*)(srw + (size_t)(k0 + r) * 512 + n0 + c);
            T[r][c + 0] = v.x; T[r][c + 1] = v.y; T[r][c + 2] = v.z; T[r][c + 3] = v.w;
        }
        __syncthreads();
        {
            const int j = t >> 3, i0 = (t & 7) * 4;
            f16x4 o;
            o[0] = (_Float16)T[i0 + 0][j];
            o[1] = (_Float16)T[i0 + 1][j];
            o[2] = (_Float16)T[i0 + 2][j];
            o[3] = (_Float16)T[i0 + 3][j];
            *(f16x4*)(srwt + (size_t)(n0 + j) * 2048 + k0 + i0) = o;
        }
        return;
    }
}

// ---------------------------------------------------------------------------
// fp16 MFMA GEMM body, NBUF-deep pipeline, counted vmcnt, ONE raw barrier
// per K-step (T3+T4). P=NBUF-1 tiles in flight. (Used by convq + out-proj.)
// ---------------------------------------------------------------------------
template<int MODE, bool CONV, int BM>
__device__ __forceinline__ void gemm_body(
    const int bx, const int by,
    const _Float16* __restrict__ A, const _Float16* __restrict__ Wt,
    const float* __restrict__ bias, const float* __restrict__ bias2,
    void* __restrict__ Cv, void* __restrict__ Cv2,
    _Float16* __restrict__ As, _Float16* __restrict__ Ws)
{
    constexpr int K = CONV ? 2048 : 512;
    constexpr int NIT = K / 32;
    constexpr int MT = BM / 32;          // row-tiles per wave
    constexpr int AI = BM / 64;          // A staging instrs per wave
    constexpr int ABUF = BM * 32;        // elems per A buffer
    constexpr int NBUF = (BM == 64) ? 4 : 3;
    constexpr int P = NBUF - 1;          // tiles in flight
    constexpr int L = AI + 2;            // loads per stage per wave
    const int tid = threadIdx.x;
    const int wave = tid >> 6, lane = tid & 63;
    const int quad = lane >> 4, l15 = lane & 15;
    const int wm = wave >> 1, wn = wave & 1;
    const int wrow = wm * (BM / 2);
    const int m0 = by * BM, n0 = bx * 128;

    // ---- hoisted staging bases (k-independent) ----
    const _Float16* abase[AI];
    int ac8[AI];
    #pragma unroll
    for (int t = 0; t < AI; ++t) {
        const int e = (wave * AI + t) * 64 + lane;
        const int row = e >> 2, c8 = (e & 3) * 8;
        ac8[t] = c8;
        if (CONV) {
            const int grow = m0 + row;
            const int b = grow >> 10, rem = grow & 1023;
            const int oh = rem >> 5, ow = rem & 31;
            abase[t] = A + ((size_t)((b * 64 + 2 * oh) * 64) + 2 * ow) * 512;
        } else {
            abase[t] = A + (size_t)(m0 + row) * K + c8;
        }
    }
    const _Float16* wbase[2];
    #pragma unroll
    for (int t = 0; t < 2; ++t) {
        const int e = (wave * 2 + t) * 64 + lane;
        const int row = e >> 2, c8 = (e & 3) * 8;
        wbase[t] = Wt + (size_t)(n0 + row) * K + c8;
    }

    auto stage = [&](const int k0, const int buf) {
        #pragma unroll
        for (int t = 0; t < AI; ++t) {
            const _Float16* gp;
            if (CONV) {
                const int gk = k0 + ac8[t];
                gp = abase[t] + ((gk >> 10) & 1) * 32768 + ((gk >> 9) & 1) * 512
                              + (gk & 511);
            } else {
                gp = abase[t] + k0;
            }
            gload_lds16(gp, &As[buf * ABUF + (wave * AI + t) * 512]);
        }
        #pragma unroll
        for (int t = 0; t < 2; ++t)
            gload_lds16(wbase[t] + k0, &Ws[buf * 4096 + (wave * 2 + t) * 512]);
    };

    f32x4 acc[MT][4] = {};

    #pragma unroll
    for (int p = 0; p < P; ++p) stage(p * 32, p);

    int cur = 0, nxt = P % NBUF;
    for (int it = 0; it < NIT; ++it) {
        int rem = NIT - 1 - it;
        if (rem > P - 1) rem = P - 1;
        switch (rem) {                       // tile it landed; newer stay in flight
            case 0:  wait_vm<0>(); break;
            case 1:  wait_vm<L>(); break;
            case 2:  wait_vm<2 * L>(); break;
            default: wait_vm<3 * L>(); break;
        }
        __builtin_amdgcn_s_barrier();
        __builtin_amdgcn_sched_barrier(0);
        if (it + P < NIT) {
            stage((it + P) * 32, nxt);
            nxt = (nxt + 1 == NBUF) ? 0 : nxt + 1;
        }

        f16x8 af[MT], bf[4];
        #pragma unroll
        for (int mt = 0; mt < MT; ++mt)
            af[mt] = *(const f16x8*)&As[cur * ABUF + (wrow + mt * 16 + l15) * 32 + quad * 8];
        #pragma unroll
        for (int nt = 0; nt < 4; ++nt)
            bf[nt] = *(const f16x8*)&Ws[cur * 4096 + (wn * 64 + nt * 16 + l15) * 32 + quad * 8];
        #pragma unroll
        for (int mt = 0; mt < MT; ++mt)
            #pragma unroll
            for (int nt = 0; nt < 4; ++nt)
                acc[mt][nt] = __builtin_amdgcn_mfma_f32_16x16x32_f16(
                    af[mt], bf[nt], acc[mt][nt], 0, 0, 0);

        cur = (cur + 1 == NBUF) ? 0 : cur + 1;
    }

    // ---- epilogue: C/D layout col=lane&15, row=quad*4+reg ----
    #pragma unroll
    for (int nt = 0; nt < 4; ++nt) {
        const int gcol = n0 + wn * 64 + nt * 16 + l15;
        float bv;
        if (MODE == 6) bv = bias[(gcol & 63) * 8 + (gcol >> 6)];
        else bv = bias[gcol];
        #pragma unroll
        for (int mt = 0; mt < MT; ++mt) {
            const int row0 = m0 + wrow + mt * 16 + quad * 4;
            if (MODE == 0) {
                #pragma unroll
                for (int r = 0; r < 4; ++r)
                    ((float*)Cv)[(size_t)(row0 + r) * 512 + gcol] = acc[mt][nt][r] + bv;
            } else {
                #pragma unroll
                for (int r = 0; r < 4; ++r)
                    ((_Float16*)Cv)[(size_t)(row0 + r) * 512 + gcol] =
                        (_Float16)(acc[mt][nt][r] + bv);
            }
        }
    }
}

// ---------------------------------------------------------------------------
// Fused conv (im2col GEMM, ids [0,256)) + Q projection (ids [256,768)).
// XCD-aware remap (T1): within each segment, by=(g&7)+8*(g>>5), bx=(g>>3)&3
// -> the 4 column-blocks sharing one A-row panel land on ONE XCD (linear%8
// is invariant in bx), so A re-reads hit that XCD's L2 (~200cy) instead of
// L3/HBM (~900cy). Per-XCD footprint ~2MB A + weights < 4MB L2.
// ---------------------------------------------------------------------------
__global__ __launch_bounds__(256)
void convq_k(const _Float16* __restrict__ xh, const _Float16* __restrict__ srwt,
             const float* __restrict__ srb, const _Float16* __restrict__ wqt,
             const float* __restrict__ bq,
             _Float16* __restrict__ kvh, _Float16* __restrict__ qh)
{
    __shared__ __align__(16) _Float16 lds[24576];   // 48 KB
    const int id = blockIdx.x;
    if (id < 256) {        // conv: K=2048, NBUF=4, by in [0,64)
        const int by = (id & 7) + 8 * (id >> 5);
        const int bx = (id >> 3) & 3;
        gemm_body<4, true, 64>(bx, by, xh, srwt, srb, nullptr,
                               kvh, nullptr, lds, lds + 4 * 64 * 32);
    } else {               // Q proj: NBUF=3, by in [0,128)
        const int g2 = id - 256;
        const int by = (g2 & 7) + 8 * (g2 >> 5);
        const int bx = (g2 >> 3) & 3;
        gemm_body<6, false, 128>(bx, by, xh, wqt, bq, nullptr,
                                 qh, nullptr, lds, lds + 3 * 128 * 32);
    }
}

// ---------------------------------------------------------------------------
// Output projection, 1-D grid 512 with the same XCD remap (atth row-panels
// shared by 4 column-blocks -> co-XCD).
// ---------------------------------------------------------------------------
__global__ __launch_bounds__(256)
void outproj_k(const _Float16* __restrict__ A, const _Float16* __restrict__ Wt,
               const float* __restrict__ bias, float* __restrict__ C)
{
    __shared__ __align__(16) _Float16 lds[24576];   // 48 KB
    const int g = blockIdx.x;
    const int by = (g & 7) + 8 * (g >> 5);
    const int bx = (g >> 3) & 3;
    gemm_body<0, false, 128>(bx, by, A, Wt, bias, nullptr,
                             C, nullptr, lds, lds + 3 * 128 * 32);
}

// ---------------------------------------------------------------------------
// LN-fused KV projection. grid (8,64), 256 thr, 2 blocks/CU (80KB LDS).
// (blockIdx.x = bx already gives linear%8 = bx -> same-W blocks co-XCD.)
// Phase 1: LN per row into a resident XOR-swizzled 64KB LDS tile.
// Phase 2: K-loop, zero A staging, 8KB W dbuf. Epilogue = MODE 5.
// ---------------------------------------------------------------------------
__global__ __launch_bounds__(256)
void kvln_k(const _Float16* __restrict__ A, const _Float16* __restrict__ Wt,
            const float* __restrict__ lng, const float* __restrict__ lnb,
            const float* __restrict__ biask, const float* __restrict__ biasv,
            _Float16* __restrict__ kh, _Float16* __restrict__ vh)
{
    __shared__ __align__(16) _Float16 Al[64 * 512];    // 64KB resident A
    __shared__ __align__(16) _Float16 Ws[2 * 4096];    // 16KB W dbuf
    const int bx = blockIdx.x, by = blockIdx.y;
    const int tid = threadIdx.x;
    const int wave = tid >> 6, lane = tid & 63;
    const int quad = lane >> 4, l15 = lane & 15;
    const int wm = wave >> 1, wn = wave & 1;
    const int wrow = wm * 32;
    const int m0 = by * 64, n0 = bx * 128;

    // ---- W staging (identical layout to gemm_body) ----
    const _Float16* wbase[2];
    #pragma unroll
    for (int t = 0; t < 2; ++t) {
        const int e = (wave * 2 + t) * 64 + lane;
        const int row = e >> 2, c8 = (e & 3) * 8;
        wbase[t] = Wt + (size_t)(n0 + row) * 512 + c8;
    }
    auto stageW = [&](const int k0, const int buf) {
        #pragma unroll
        for (int t = 0; t < 2; ++t)
            gload_lds16(wbase[t] + k0, &Ws[buf * 4096 + (wave * 2 + t) * 512]);
    };
    stageW(0, 0);                           // W tile 0 flies during LN phase

    // ---- Phase 1: load A, LayerNorm, swizzled resident store ----
    const int colt = (tid & 63) * 8;        // fixed column span per thread
    float g[8], bb[8];
    {
        const float4 g0 = *(const float4*)(lng + colt);
        const float4 g1 = *(const float4*)(lng + colt + 4);
        const float4 b0 = *(const float4*)(lnb + colt);
        const float4 b1 = *(const float4*)(lnb + colt + 4);
        g[0] = g0.x; g[1] = g0.y; g[2] = g0.z; g[3] = g0.w;
        g[4] = g1.x; g[5] = g1.y; g[6] = g1.z; g[7] = g1.w;
        bb[0] = b0.x; bb[1] = b0.y; bb[2] = b0.z; bb[3] = b0.w;
        bb[4] = b1.x; bb[5] = b1.y; bb[6] = b1.z; bb[7] = b1.w;
    }
    const _Float16* ab = A + (size_t)m0 * 512;
    #pragma unroll
    for (int r4 = 0; r4 < 4; ++r4) {
        float f[4][8]; float mu[4], rs[4];
        #pragma unroll
        for (int i = 0; i < 4; ++i) {
            const int c = (r4 * 4 + i) * 256 + tid;
            const f16x8 d = *(const f16x8*)(ab + (size_t)c * 8);
            #pragma unroll
            for (int e = 0; e < 8; ++e) f[i][e] = (float)d[e];
        }
        #pragma unroll
        for (int i = 0; i < 4; ++i) {
            float s = 0.f, q = 0.f;
            #pragma unroll
            for (int e = 0; e < 8; ++e) { s += f[i][e]; q += f[i][e] * f[i][e]; }
            #pragma unroll
            for (int off = 32; off > 0; off >>= 1) {
                s += __shfl_xor(s, off);
                q += __shfl_xor(q, off);
            }
            mu[i] = s * (1.f / 512.f);
            rs[i] = rsqrtf(fmaxf(q * (1.f / 512.f) - mu[i] * mu[i], 0.f) + 1e-6f);
        }
        #pragma unroll
        for (int i = 0; i < 4; ++i) {
            const int row = (r4 * 4 + i) * 4 + wave;   // == c>>6
            f16x8 o;
            #pragma unroll
            for (int e = 0; e < 8; ++e)
                o[e] = (_Float16)((f[i][e] - mu[i]) * rs[i] * g[e] + bb[e]);
            const int boff = (row * 1024 + colt * 2) ^ ((row & 7) << 4);
            *(f16x8*)((char*)Al + boff) = o;
        }
    }
    __syncthreads();                        // Al valid; W tile 0 landed too

    // ---- Phase 2: K-loop, A resident, W dbuf ----
    f32x4 acc[2][4] = {};
    int cur = 0;
    for (int it = 0; it < 16; ++it) {
        if (it) {
            wait_vm<0>();                   // W[cur] landed
            __builtin_amdgcn_s_barrier();   // prev readers of other buf done
        }
        if (it + 1 < 16) stageW((it + 1) * 32, cur ^ 1);
        const int k0 = it * 32;
        f16x8 af[2], bf[4];
        #pragma unroll
        for (int mt = 0; mt < 2; ++mt) {
            const int row = wrow + mt * 16 + l15;
            const int boff = (row * 1024 + k0 * 2 + quad * 16) ^ ((row & 7) << 4);
            af[mt] = *(const f16x8*)((const char*)Al + boff);
        }
        #pragma unroll
        for (int nt = 0; nt < 4; ++nt)
            bf[nt] = *(const f16x8*)&Ws[cur * 4096 + (wn * 64 + nt * 16 + l15) * 32 + quad * 8];
        #pragma unroll
        for (int mt = 0; mt < 2; ++mt)
            #pragma unroll
            for (int nt = 0; nt < 4; ++nt)
                acc[mt][nt] = __builtin_amdgcn_mfma_f32_16x16x32_f16(
                    af[mt], bf[nt], acc[mt][nt], 0, 0, 0);
        cur ^= 1;
    }

    // ---- epilogue: MODE 5 (k<512 head-perm'd -> kh; else v^T -> vh) ----
    #pragma unroll
    for (int nt = 0; nt < 4; ++nt) {
        const int gcol = n0 + wn * 64 + nt * 16 + l15;
        const float bv = (gcol < 512) ? biask[(gcol & 63) * 8 + (gcol >> 6)]
                                      : biasv[gcol - 512];
        #pragma unroll
        for (int mt = 0; mt < 2; ++mt) {
            const int row0 = m0 + wrow + mt * 16 + quad * 4;
            if (gcol < 512) {
                #pragma unroll
                for (int r = 0; r < 4; ++r)
                    kh[(size_t)(row0 + r) * 512 + gcol] =
                        (_Float16)(acc[mt][nt][r] + bv);
            } else {
                const int c = gcol - 512;
                const int h = c & 7, d = c >> 3;
                const int b_ = row0 >> 10, jj = row0 & 1023;
                f16x4 o;
                #pragma unroll
                for (int r = 0; r < 4; ++r) o[r] = (_Float16)(acc[mt][nt][r] + bv);
                *(f16x4*)(vh + ((size_t)(b_ * 8 + h) * 64 + d) * 1024 + jj) = o;
            }
        }
    }
}

// ---------------------------------------------------------------------------
// MFMA flash attention (R8 body): 8 waves, 512 q-rows/block, 4 subtiles,
// perm'd-K x32 PV, ones-MFMA l-sum. 1-D grid 256 with XCD remap so the 8
// q-blocks sharing one head's 256KB K/V land on one XCD (4 heads/XCD = 1MB).
// ---------------------------------------------------------------------------
__global__ __launch_bounds__(512)
void attn_mfma_k(const _Float16* __restrict__ qb,
                 const _Float16* __restrict__ kbuf,
                 const _Float16* __restrict__ vbuf,
                 _Float16* __restrict__ out)
{
    const int g = blockIdx.x;            // 0..255
    const int bh = (g & 7) + ((g >> 6) << 3);   // 0..31, co-XCD per head
    const int qt = (g >> 3) & 7;         // 0..7
    const int b = bh >> 3, h = bh & 7;
    const int tid = threadIdx.x;
    const int wave = tid >> 6, lane = tid & 63;
    const int quad = lane >> 4, l15 = lane & 15;

    __shared__ __align__(16) _Float16 Ks[2][64 * 72];   // [perm'd key][d]
    __shared__ __align__(16) _Float16 Vs[2][64 * 72];   // [d][key]

    // ---- Q frags (B operand), pre-scaled by 0.125*log2(e) ----
    const int qrow = b * 4096 + qt * 512 + wave * 64 + l15;
    const _Float16* qp = qb + (size_t)qrow * 512 + h * 64 + quad * 8;
    f16x8 qf[4][2];
    #pragma unroll
    for (int su = 0; su < 4; ++su) {
        qf[su][0] = *(const f16x8*)(qp + su * 16 * 512);
        qf[su][1] = *(const f16x8*)(qp + su * 16 * 512 + 32);
    }
    {
        const _Float16 qs = (_Float16)0.18033688f;
        #pragma unroll
        for (int su = 0; su < 4; ++su)
            #pragma unroll
            for (int gg = 0; gg < 2; ++gg)
                #pragma unroll
                for (int i = 0; i < 8; ++i) qf[su][gg][i] *= qs;
    }

    // ---- ones B-frag for the l-sum MFMA ----
    f16x8 ones;
    #pragma unroll
    for (int i = 0; i < 8; ++i) ones[i] = (_Float16)1.0f;

    // ---- staging pointers: 512 thr x 16B = one 64x64 fp16 tile ----
    const int kr = tid >> 3, kc = (tid & 7) * 8;
    // permuted K LDS row: key kr -> row so S^T lands pre-arranged for x32 PV
    const int krp = (kr & 32) | ((kr & 4) << 2) | ((kr >> 1) & 12) | (kr & 3);
    const _Float16* kg = kbuf + (size_t)(b * 1024 + kr) * 512 + h * 64 + kc;
    const _Float16* vg = vbuf + (size_t)(bh * 64 + kr) * 1024 + kc;

    f16x8 krg = *(const f16x8*)kg;
    f16x8 vrg = *(const f16x8*)vg;
    *(f16x8*)&Ks[0][krp * 72 + kc] = krg;
    *(f16x8*)&Vs[0][kr * 72 + kc] = vrg;

    f32x4 acc[4][4] = {};
    f32x4 acc_l[4] = {};

    for (int kt = 0; kt < 16; ++kt) {
        const int cur = kt & 1;
        __syncthreads();                               // buf[cur] staged, buf[cur^1] free
        if (kt < 15) {                                 // prefetch next chunk
            krg = *(const f16x8*)(kg + (size_t)(kt + 1) * 64 * 512);
            vrg = *(const f16x8*)(vg + (kt + 1) * 64);
        }

        // ---- per 32-key block: swapped QK^T -> exp2 -> x32 PV ----
        #pragma unroll
        for (int kb = 0; kb < 2; ++kb) {
            f16x8 pa[4];                               // P A-frags (8 keys/lane)
            #pragma unroll
            for (int c = 0; c < 2; ++c) {
                const int ct = kb * 2 + c;
                const f16x8 kf0 = *(const f16x8*)&Ks[cur][(ct * 16 + l15) * 72 + quad * 8];
                const f16x8 kf1 = *(const f16x8*)&Ks[cur][(ct * 16 + l15) * 72 + 32 + quad * 8];
                #pragma unroll
                for (int su = 0; su < 4; ++su) {
                    f32x4 s = {};
                    s = __builtin_amdgcn_mfma_f32_16x16x32_f16(kf0, qf[su][0], s, 0, 0, 0);
                    s = __builtin_amdgcn_mfma_f32_16x16x32_f16(kf1, qf[su][1], s, 0, 0, 0);
                    pa[su][c * 4 + 0] = (_Float16)EXP2F(s[0]);
                    pa[su][c * 4 + 1] = (_Float16)EXP2F(s[1]);
                    pa[su][c * 4 + 2] = (_Float16)EXP2F(s[2]);
                    pa[su][c * 4 + 3] = (_Float16)EXP2F(s[3]);
                }
            }
            __builtin_amdgcn_s_setprio(1);
            #pragma unroll
            for (int su = 0; su < 4; ++su)
                acc_l[su] = __builtin_amdgcn_mfma_f32_16x16x32_f16(
                    pa[su], ones, acc_l[su], 0, 0, 0);
            #pragma unroll
            for (int nt = 0; nt < 4; ++nt) {
                const f16x8 vf = *(const f16x8*)&Vs[cur][(nt * 16 + l15) * 72 + kb * 32 + quad * 8];
                #pragma unroll
                for (int su = 0; su < 4; ++su)
                    acc[su][nt] = __builtin_amdgcn_mfma_f32_16x16x32_f16(
                        pa[su], vf, acc[su][nt], 0, 0, 0);
            }
            __builtin_amdgcn_s_setprio(0);
        }

        if (kt < 15) {                                 // write prefetch -> other buf
            *(f16x8*)&Ks[cur ^ 1][krp * 72 + kc] = krg;
            *(f16x8*)&Vs[cur ^ 1][kr * 72 + kc] = vrg;
        }
    }

    // ---- epilogue: l[q] sits in acc_l[su][r] at exactly (quad,r) of row q ----
    #pragma unroll
    for (int su = 0; su < 4; ++su) {
        float inv[4];
        #pragma unroll
        for (int r = 0; r < 4; ++r) inv[r] = 1.0f / acc_l[su][r];
        #pragma unroll
        for (int nt = 0; nt < 4; ++nt)
            #pragma unroll
            for (int r = 0; r < 4; ++r) {
                const int row = qt * 512 + wave * 64 + su * 16 + quad * 4 + r;
                const int col = h * 64 + nt * 16 + l15;
                out[((size_t)b * 4096 + row) * 512 + col] =
                    (_Float16)(acc[su][nt][r] * inv[r]);
            }
    }
}

// ---------------------------------------------------------------------------
extern "C" void kernel_launch(void* const* d_in, const int* in_sizes, int n_in,
                              void* d_out, int out_size, void* d_ws, size_t ws_size,
                              hipStream_t stream)
{
    const float* x   = (const float*)d_in[0];
    const float* Wq  = (const float*)d_in[1];
    const float* bq  = (const float*)d_in[2];
    const float* Wk  = (const float*)d_in[3];
    const float* bk  = (const float*)d_in[4];
    const float* Wv  = (const float*)d_in[5];
    const float* bv  = (const float*)d_in[6];
    const float* Wp  = (const float*)d_in[7];
    const float* bp  = (const float*)d_in[8];
    const float* srw = (const float*)d_in[9];
    const float* srb = (const float*)d_in[10];
    const float* lng = (const float*)d_in[11];
    const float* lnb = (const float*)d_in[12];

    _Float16* ws   = (_Float16*)d_ws;
    _Float16* xh   = ws;                    // 8,388,608  (16.8 MB)
    _Float16* atth = xh + 8388608;          // 8,388,608  (16.8 MB)
    _Float16* kvh  = atth + 8388608;        // 2,097,152  (4.2 MB)
    _Float16* kh   = kvh + 2097152;         // 2,097,152  (4.2 MB)
    _Float16* vh   = kh + 2097152;          // 2,097,152  (4.2 MB)
    _Float16* wqt  = vh + 2097152;          // 262,144
    _Float16* wkvt = wqt + 262144;          // 524,288 (Wk perm'd | Wv plain)
    _Float16* wpt  = wkvt + 524288;         // 262,144
    _Float16* srwt = wpt + 262144;          // 1,048,576
    _Float16* qh   = (_Float16*)d_out;      // q scratch in d_out

    // 1. fused prep: cvt + 4x weight transpose + srw transpose
    prep_k<<<6144, 256, 0, stream>>>(x, Wq, Wk, Wv, Wp, srw,
                                     xh, wqt, wkvt, wpt, srwt);
    // 2. fused conv (im2col GEMM) + Q projection, XCD-swizzled
    convq_k<<<768, 256, 0, stream>>>(xh, srwt, srb, wqt, bq, kvh, qh);
    // 3. LN-fused K+V projections (512 blocks, 2/CU, A resident in LDS)
    kvln_k<<<dim3(8, 64), 256, 0, stream>>>(kvh, wkvt, lng, lnb, bk, bv, kh, vh);
    // 4. MFMA flash attention, XCD-swizzled (co-XCD per head)
    attn_mfma_k<<<256, 512, 0, stream>>>(qh, kh, vh, atth);
    // 5. output projection -> d_out fp32, XCD-swizzled
    outproj_k<<<512, 256, 0, stream>>>(atth, wpt, bp, (float*)d_out);
}